// Round 1
// baseline (216.350 us; speedup 1.0000x reference)
//
#include <hip/hip_runtime.h>
#include <math.h>

// Problem constants (fixed by the reference).
#define BB 8
#define LL 12
#define TT 36
#define DD 1024
#define FF 3
#define CC 32

// ---------------------------------------------------------------------------
// K1: q transposed -> ws.  qT[bl][d][c] = Wq[c]·x_local[bl,d,:] + bq[c]
// Lanes = channels (coalesced 128B writes); x_local broadcast per d.
// ---------------------------------------------------------------------------
__global__ __launch_bounds__(256) void k_qT(const float* __restrict__ xl,
                                            const float* __restrict__ Wq,
                                            const float* __restrict__ bq,
                                            float* __restrict__ qT) {
  const int bl = blockIdx.x;            // b*L + l, 0..95
  const int c  = threadIdx.x & 31;
  const int ds = threadIdx.x >> 5;      // 0..7
  const float w0 = Wq[c * 3 + 0], w1 = Wq[c * 3 + 1], w2 = Wq[c * 3 + 2];
  const float b0 = bq[c];
  const float* xrow = xl + (size_t)bl * DD * FF;
  float* qrow = qT + (size_t)bl * DD * CC;
  for (int db = 0; db < DD / 8; ++db) {
    const int d = db * 8 + ds;
    const float x0 = xrow[d * 3 + 0];
    const float x1 = xrow[d * 3 + 1];
    const float x2 = xrow[d * 3 + 2];
    qrow[d * CC + c] = fmaf(w0, x0, fmaf(w1, x1, fmaf(w2, x2, b0)));
  }
}

// ---------------------------------------------------------------------------
// K2: scores mq[bl][c][t] = sum_d (Wm[c]·x_hist[bl,t,d,:] + bm[c]) * q[c,d]
// Block = (bl, t-quarter); 288 threads = 32 channels x 9 t.
// Thread owns full D loop -> zero cross-thread reduction.
// x_hist float4-vectorized, broadcast across the 32 channel lanes.
// qT read is a coalesced 128B segment per d.
// ---------------------------------------------------------------------------
__global__ __launch_bounds__(288) void k_mq(const float* __restrict__ xh,
                                            const float* __restrict__ qT,
                                            const float* __restrict__ Wm,
                                            const float* __restrict__ bm,
                                            float* __restrict__ mq) {
  const int bl = blockIdx.x;            // 0..95
  const int tq = blockIdx.y;            // 0..3
  const int c  = threadIdx.x & 31;
  const int tl = threadIdx.x >> 5;      // 0..8
  const int t  = tq * 9 + tl;
  const float w0 = Wm[c * 3 + 0], w1 = Wm[c * 3 + 1], w2 = Wm[c * 3 + 2];
  const float b0 = bm[c];
  const float4* xr = (const float4*)(xh + ((size_t)bl * TT + t) * DD * FF);
  const float* qrow = qT + (size_t)bl * DD * CC + c;
  float acc = 0.f;
  #pragma unroll 4
  for (int g = 0; g < DD / 4; ++g) {
    const float4 a  = xr[g * 3 + 0];
    const float4 bv = xr[g * 3 + 1];
    const float4 cv = xr[g * 3 + 2];
    const int d0 = g * 4;
    const float q0 = qrow[(size_t)(d0 + 0) * CC];
    const float q1 = qrow[(size_t)(d0 + 1) * CC];
    const float q2 = qrow[(size_t)(d0 + 2) * CC];
    const float q3 = qrow[(size_t)(d0 + 3) * CC];
    const float m0 = fmaf(w0, a.x,  fmaf(w1, a.y,  fmaf(w2, a.z,  b0)));
    const float m1 = fmaf(w0, a.w,  fmaf(w1, bv.x, fmaf(w2, bv.y, b0)));
    const float m2 = fmaf(w0, bv.z, fmaf(w1, bv.w, fmaf(w2, cv.x, b0)));
    const float m3 = fmaf(w0, cv.y, fmaf(w1, cv.z, fmaf(w2, cv.w, b0)));
    acc = fmaf(m0, q0, acc);
    acc = fmaf(m1, q1, acc);
    acc = fmaf(m2, q2, acc);
    acc = fmaf(m3, q3, acc);
  }
  mq[((size_t)bl * CC + c) * TT + t] = acc;
}

// ---------------------------------------------------------------------------
// K3: softmax(relu(mq)) + memory read + residual.
// Block = (bl, d-chunk of 128).  Prologue: 32 threads build att[c][40] in LDS
// (padded to 40 -> 160B rows, 16B aligned for float4 broadcast reads).
// Main: thread owns one d; 32 channel accumulators in registers; t tiled x4.
// q recomputed from x_local (3 FMA/channel). Output write coalesced per c.
// ---------------------------------------------------------------------------
__global__ __launch_bounds__(128) void k_out(const float* __restrict__ xl,
                                             const float* __restrict__ xh,
                                             const float* __restrict__ mq,
                                             const float* __restrict__ Wq,
                                             const float* __restrict__ bq,
                                             const float* __restrict__ Wc,
                                             const float* __restrict__ bc,
                                             float* __restrict__ out) {
  __shared__ __align__(16) float att[CC][40];
  const int bl = blockIdx.x;            // 0..95
  const int b = bl / LL, l = bl % LL;
  const int dc = blockIdx.y;            // 0..7
  const int tid = threadIdx.x;

  if (tid < CC) {
    const int c = tid;
    const float* row = mq + ((size_t)bl * CC + c) * TT;
    float mx = 0.f;  // relu output >= 0, so 0 is a valid max seed
    #pragma unroll
    for (int t = 0; t < TT; ++t) {
      const float r = fmaxf(row[t], 0.f);
      att[c][t] = r;
      mx = fmaxf(mx, r);
    }
    float s = 0.f;
    #pragma unroll
    for (int t = 0; t < TT; ++t) {
      const float e = __expf(att[c][t] - mx);
      att[c][t] = e;
      s += e;
    }
    const float inv = 1.f / s;
    #pragma unroll
    for (int t = 0; t < TT; ++t) att[c][t] *= inv;
    #pragma unroll
    for (int t = TT; t < 40; ++t) att[c][t] = 0.f;
  }
  __syncthreads();

  const int d = dc * 128 + tid;
  const float xl0 = xl[((size_t)bl * DD + d) * 3 + 0];
  const float xl1 = xl[((size_t)bl * DD + d) * 3 + 1];
  const float xl2 = xl[((size_t)bl * DD + d) * 3 + 2];

  float oacc[CC];
  #pragma unroll
  for (int c = 0; c < CC; ++c) oacc[c] = 0.f;

  for (int tb = 0; tb < TT / 4; ++tb) {   // 9 tiles of 4 t
    float xr[4][3];
    #pragma unroll
    for (int j = 0; j < 4; ++j) {
      const float* p = xh + (((size_t)bl * TT + tb * 4 + j) * DD + d) * 3;
      xr[j][0] = p[0];
      xr[j][1] = p[1];
      xr[j][2] = p[2];
    }
    #pragma unroll
    for (int c = 0; c < CC; ++c) {
      const float wc0 = Wc[c * 3 + 0], wc1 = Wc[c * 3 + 1], wc2 = Wc[c * 3 + 2];
      const float bcv = bc[c];
      const float4 av = *(const float4*)&att[c][tb * 4];
      oacc[c] = fmaf(av.x, fmaf(wc0, xr[0][0], fmaf(wc1, xr[0][1], fmaf(wc2, xr[0][2], bcv))), oacc[c]);
      oacc[c] = fmaf(av.y, fmaf(wc0, xr[1][0], fmaf(wc1, xr[1][1], fmaf(wc2, xr[1][2], bcv))), oacc[c]);
      oacc[c] = fmaf(av.z, fmaf(wc0, xr[2][0], fmaf(wc1, xr[2][1], fmaf(wc2, xr[2][2], bcv))), oacc[c]);
      oacc[c] = fmaf(av.w, fmaf(wc0, xr[3][0], fmaf(wc1, xr[3][1], fmaf(wc2, xr[3][2], bcv))), oacc[c]);
    }
  }

  #pragma unroll
  for (int c = 0; c < CC; ++c) {
    const float q = fmaf(Wq[c * 3 + 0], xl0,
                    fmaf(Wq[c * 3 + 1], xl1,
                    fmaf(Wq[c * 3 + 2], xl2, bq[c])));
    out[(((size_t)b * CC + c) * LL + l) * DD + d] = q + oacc[c];
  }
}

// ---------------------------------------------------------------------------
extern "C" void kernel_launch(void* const* d_in, const int* in_sizes, int n_in,
                              void* d_out, int out_size, void* d_ws, size_t ws_size,
                              hipStream_t stream) {
  const float* xl = (const float*)d_in[0];  // (B,L,D,F)
  const float* xh = (const float*)d_in[1];  // (B,L,T,D,F)
  const float* Wq = (const float*)d_in[2];
  const float* bq = (const float*)d_in[3];
  const float* Wm = (const float*)d_in[4];
  const float* bm = (const float*)d_in[5];
  const float* Wc = (const float*)d_in[6];
  const float* bc = (const float*)d_in[7];
  float* out = (float*)d_out;               // (B,C,L,D)

  float* qT  = (float*)d_ws;                            // B*L*D*C floats
  float* mqw = qT + (size_t)BB * LL * DD * CC;          // B*L*C*T floats

  k_qT <<<dim3(BB * LL),     256, 0, stream>>>(xl, Wq, bq, qT);
  k_mq <<<dim3(BB * LL, 4),  288, 0, stream>>>(xh, qT, Wm, bm, mqw);
  k_out<<<dim3(BB * LL, 8),  128, 0, stream>>>(xl, xh, mqw, Wq, bq, Wc, bc, out);
}

// Round 2
// 167.082 us; speedup vs baseline: 1.2949x; 1.2949x over previous
//
#include <hip/hip_runtime.h>
#include <math.h>

// Problem constants (fixed by the reference).
#define BB 8
#define LL 12
#define TT 36
#define DD 1024
#define FF 3
#define CC 32

// ---------------------------------------------------------------------------
// K1: q transposed -> ws.  qT[bl][d][c] = Wq[c]·x_local[bl,d,:] + bq[c]
// grid (96, 8): 768 blocks (12 waves/CU). Lanes = channels (128B coalesced
// writes); x_local broadcast per d.
// ---------------------------------------------------------------------------
__global__ __launch_bounds__(256) void k_qT(const float* __restrict__ xl,
                                            const float* __restrict__ Wq,
                                            const float* __restrict__ bq,
                                            float* __restrict__ qT) {
  const int bl = blockIdx.x;            // 0..95
  const int c  = threadIdx.x & 31;
  const int s  = threadIdx.x >> 5;      // 0..7
  const float w0 = Wq[c * 3 + 0], w1 = Wq[c * 3 + 1], w2 = Wq[c * 3 + 2];
  const float b0 = bq[c];
  const float* xrow = xl + (size_t)bl * DD * FF;
  float* qrow = qT + (size_t)bl * DD * CC;
  const int d0 = blockIdx.y * 128 + s * 16;
  #pragma unroll
  for (int k = 0; k < 16; ++k) {
    const int d = d0 + k;
    const float x0 = xrow[d * 3 + 0];
    const float x1 = xrow[d * 3 + 1];
    const float x2 = xrow[d * 3 + 2];
    qrow[d * CC + c] = fmaf(w0, x0, fmaf(w1, x1, fmaf(w2, x2, b0)));
  }
}

// ---------------------------------------------------------------------------
// K2: scores mq[bl][c][t] = sum_d (Wm[c]·x_hist[bl,t,d,:] + bm[c]) * q[c,d]
// grid (96, 36): one block per (bl,t) -> 3456 blocks (54 waves/CU demanded).
// 256 threads = 32 channels x 8 d-segments of 128 d each.
// 8-way LDS reduction per channel (padded stride 9 -> conflict-free).
// ---------------------------------------------------------------------------
__global__ __launch_bounds__(256) void k_mq(const float* __restrict__ xh,
                                            const float* __restrict__ qT,
                                            const float* __restrict__ Wm,
                                            const float* __restrict__ bm,
                                            float* __restrict__ mq) {
  __shared__ float red[CC * 9];
  const int bl = blockIdx.x;            // 0..95
  const int t  = blockIdx.y;            // 0..35
  const int c  = threadIdx.x & 31;
  const int s  = threadIdx.x >> 5;      // 0..7
  const float w0 = Wm[c * 3 + 0], w1 = Wm[c * 3 + 1], w2 = Wm[c * 3 + 2];
  const float b0 = bm[c];
  const float4* xr = (const float4*)(xh + ((size_t)bl * TT + t) * DD * FF);
  const float* qrow = qT + (size_t)bl * DD * CC + c;

  float acc0 = 0.f, acc1 = 0.f;
  const int dbase = s * 128;
  #pragma unroll 4
  for (int it = 0; it < 32; ++it) {     // 4 d per iteration
    const int d0 = dbase + it * 4;
    const int g  = (d0 * 3) >> 2;       // float4 index
    const float4 a  = xr[g + 0];
    const float4 bv = xr[g + 1];
    const float4 cv = xr[g + 2];
    const float q0 = qrow[(d0 + 0) * CC];
    const float q1 = qrow[(d0 + 1) * CC];
    const float q2 = qrow[(d0 + 2) * CC];
    const float q3 = qrow[(d0 + 3) * CC];
    const float m0 = fmaf(w0, a.x,  fmaf(w1, a.y,  fmaf(w2, a.z,  b0)));
    const float m1 = fmaf(w0, a.w,  fmaf(w1, bv.x, fmaf(w2, bv.y, b0)));
    const float m2 = fmaf(w0, bv.z, fmaf(w1, bv.w, fmaf(w2, cv.x, b0)));
    const float m3 = fmaf(w0, cv.y, fmaf(w1, cv.z, fmaf(w2, cv.w, b0)));
    acc0 = fmaf(m0, q0, acc0);
    acc1 = fmaf(m1, q1, acc1);
    acc0 = fmaf(m2, q2, acc0);
    acc1 = fmaf(m3, q3, acc1);
  }
  red[c * 9 + s] = acc0 + acc1;
  __syncthreads();
  if (threadIdx.x < CC) {
    const int cc = threadIdx.x;
    float v = 0.f;
    #pragma unroll
    for (int j = 0; j < 8; ++j) v += red[cc * 9 + j];
    mq[((size_t)bl * CC + cc) * TT + t] = v;
  }
}

// ---------------------------------------------------------------------------
// K3: softmax(relu(mq)) + memory read + residual.
// grid (96, 16), 256 threads = 64 d-lanes x 4 t-quarters (9 t each).
// att in LDS as [t][c] (float4 broadcast reads, conflict-free).
// 4-way tg-reduction via LDS rows padded to 33 (conflict-free).
// ---------------------------------------------------------------------------
__global__ __launch_bounds__(256) void k_out(const float* __restrict__ xl,
                                             const float* __restrict__ xh,
                                             const float* __restrict__ mq,
                                             const float* __restrict__ Wq,
                                             const float* __restrict__ bq,
                                             const float* __restrict__ Wc,
                                             const float* __restrict__ bc,
                                             float* __restrict__ out) {
  __shared__ __align__(16) float att2[TT * CC];   // [t][c], 4.6 KB
  __shared__ float red[4 * 64 * 33];              // [tg][dl][c pad 33], 33.8 KB
  const int bl = blockIdx.x;            // 0..95
  const int b = bl / LL, l = bl % LL;
  const int dc = blockIdx.y;            // 0..15 (64-d chunk)
  const int tid = threadIdx.x;
  const int dl = tid & 63;
  const int tg = tid >> 6;              // 0..3

  if (tid < CC) {                       // softmax(relu(.)) for channel tid
    const int c = tid;
    const float* row = mq + ((size_t)bl * CC + c) * TT;
    float r[TT];
    float mx = 0.f;                     // relu >= 0 -> 0 is a valid max seed
    #pragma unroll
    for (int t = 0; t < TT; ++t) {
      r[t] = fmaxf(row[t], 0.f);
      mx = fmaxf(mx, r[t]);
    }
    float ssum = 0.f;
    #pragma unroll
    for (int t = 0; t < TT; ++t) {
      r[t] = __expf(r[t] - mx);
      ssum += r[t];
    }
    const float inv = 1.f / ssum;
    #pragma unroll
    for (int t = 0; t < TT; ++t) att2[t * CC + c] = r[t] * inv;
  }
  __syncthreads();

  const int d = dc * 64 + dl;
  // Load this thread's 9 t-samples of x_hist[., d, 0:3] into registers.
  float xv[9][3];
  #pragma unroll
  for (int j = 0; j < 9; ++j) {
    const int t = tg * 9 + j;
    const float* p = xh + (((size_t)bl * TT + t) * DD + d) * 3;
    xv[j][0] = p[0];
    xv[j][1] = p[1];
    xv[j][2] = p[2];
  }

  float oacc[CC];
  #pragma unroll
  for (int c = 0; c < CC; ++c) oacc[c] = 0.f;

  #pragma unroll
  for (int cg = 0; cg < 8; ++cg) {      // 4 channels at a time
    const int c0 = cg * 4;
    float w[4][3], bb[4];
    #pragma unroll
    for (int u = 0; u < 4; ++u) {
      w[u][0] = Wc[(c0 + u) * 3 + 0];
      w[u][1] = Wc[(c0 + u) * 3 + 1];
      w[u][2] = Wc[(c0 + u) * 3 + 2];
      bb[u]   = bc[c0 + u];
    }
    #pragma unroll
    for (int j = 0; j < 9; ++j) {
      const int t = tg * 9 + j;
      const float4 av = *(const float4*)&att2[t * CC + c0];  // LDS broadcast
      const float x0 = xv[j][0], x1 = xv[j][1], x2 = xv[j][2];
      oacc[c0 + 0] = fmaf(av.x, fmaf(w[0][0], x0, fmaf(w[0][1], x1, fmaf(w[0][2], x2, bb[0]))), oacc[c0 + 0]);
      oacc[c0 + 1] = fmaf(av.y, fmaf(w[1][0], x0, fmaf(w[1][1], x1, fmaf(w[1][2], x2, bb[1]))), oacc[c0 + 1]);
      oacc[c0 + 2] = fmaf(av.z, fmaf(w[2][0], x0, fmaf(w[2][1], x1, fmaf(w[2][2], x2, bb[2]))), oacc[c0 + 2]);
      oacc[c0 + 3] = fmaf(av.w, fmaf(w[3][0], x0, fmaf(w[3][1], x1, fmaf(w[3][2], x2, bb[3]))), oacc[c0 + 3]);
    }
  }

  // tg-reduction: write partials, then combine + residual + store.
  float* myrow = &red[(tg * 64 + dl) * 33];
  #pragma unroll
  for (int c = 0; c < CC; ++c) myrow[c] = oacc[c];   // bank (dl+c)%32: clean
  __syncthreads();

  {
    const int dl2 = tid & 63;
    const int cg2 = tid >> 6;           // 8 channels per thread
    const int dd = dc * 64 + dl2;
    const float x0 = xl[((size_t)bl * DD + dd) * 3 + 0];
    const float x1 = xl[((size_t)bl * DD + dd) * 3 + 1];
    const float x2 = xl[((size_t)bl * DD + dd) * 3 + 2];
    #pragma unroll
    for (int u = 0; u < 8; ++u) {
      const int c = cg2 * 8 + u;
      float v = red[(0 * 64 + dl2) * 33 + c] + red[(1 * 64 + dl2) * 33 + c] +
                red[(2 * 64 + dl2) * 33 + c] + red[(3 * 64 + dl2) * 33 + c];
      const float q = fmaf(Wq[c * 3 + 0], x0,
                      fmaf(Wq[c * 3 + 1], x1,
                      fmaf(Wq[c * 3 + 2], x2, bq[c])));
      out[(((size_t)b * CC + c) * LL + l) * DD + dd] = q + v;
    }
  }
}

// ---------------------------------------------------------------------------
extern "C" void kernel_launch(void* const* d_in, const int* in_sizes, int n_in,
                              void* d_out, int out_size, void* d_ws, size_t ws_size,
                              hipStream_t stream) {
  const float* xl = (const float*)d_in[0];  // (B,L,D,F)
  const float* xh = (const float*)d_in[1];  // (B,L,T,D,F)
  const float* Wq = (const float*)d_in[2];
  const float* bq = (const float*)d_in[3];
  const float* Wm = (const float*)d_in[4];
  const float* bm = (const float*)d_in[5];
  const float* Wc = (const float*)d_in[6];
  const float* bc = (const float*)d_in[7];
  float* out = (float*)d_out;               // (B,C,L,D)

  float* qT  = (float*)d_ws;                            // B*L*D*C floats
  float* mqw = qT + (size_t)BB * LL * DD * CC;          // B*L*C*T floats

  k_qT <<<dim3(BB * LL, 8),  256, 0, stream>>>(xl, Wq, bq, qT);
  k_mq <<<dim3(BB * LL, TT), 256, 0, stream>>>(xh, qT, Wm, bm, mqw);
  k_out<<<dim3(BB * LL, 16), 256, 0, stream>>>(xl, xh, mqw, Wq, bq, Wc, bc, out);
}

// Round 4
// 157.050 us; speedup vs baseline: 1.3776x; 1.0639x over previous
//
#include <hip/hip_runtime.h>
#include <math.h>

// Problem constants (fixed by the reference).
#define BB 8
#define LL 12
#define TT 36
#define DD 1024
#define FF 3
#define CC 32

// ---------------------------------------------------------------------------
// K1: partial scores.
// grid (96, 8) = 768 blocks; 256 threads = 32 channels x 8 d-subchunks of 16.
// Each thread computes q[c, 16d] from x_local in registers (no qT workspace),
// loops t accumulating the 16-d partial dot into LDS part[t][s][c].
// Block epilogue reduces over s and writes mqp[bl][t][dc][c]  (dc IS in the
// index now -- R3's bug was 8 dc-blocks clobbering the same slot).
// ---------------------------------------------------------------------------
__global__ __launch_bounds__(256) void k_mq(const float* __restrict__ xl,
                                            const float* __restrict__ xh,
                                            const float* __restrict__ Wm,
                                            const float* __restrict__ bm,
                                            const float* __restrict__ Wq,
                                            const float* __restrict__ bq,
                                            float* __restrict__ mqp) {
  __shared__ float part[TT][8][CC];     // 36 KB; write lane=s*32+c contiguous
  const int bl = blockIdx.x;            // 0..95
  const int dc = blockIdx.y;            // 0..7 (128-d chunk)
  const int c  = threadIdx.x & 31;
  const int s  = threadIdx.x >> 5;      // 0..7 (16-d sub)
  const int d0 = dc * 128 + s * 16;

  // q[c, d0..d0+15] in registers.
  const float wq0 = Wq[c * 3 + 0], wq1 = Wq[c * 3 + 1], wq2 = Wq[c * 3 + 2];
  const float bq0 = bq[c];
  float q[16];
  {
    const float4* xlr = (const float4*)(xl + ((size_t)bl * DD + d0) * 3);
    float4 xb[12];
    #pragma unroll
    for (int i = 0; i < 12; ++i) xb[i] = xlr[i];
    const float* x = (const float*)xb;
    #pragma unroll
    for (int k = 0; k < 16; ++k)
      q[k] = fmaf(wq0, x[k * 3 + 0], fmaf(wq1, x[k * 3 + 1], fmaf(wq2, x[k * 3 + 2], bq0)));
  }

  const float w0 = Wm[c * 3 + 0], w1 = Wm[c * 3 + 1], w2 = Wm[c * 3 + 2];
  const float b0 = bm[c];

  #pragma unroll 2
  for (int t = 0; t < TT; ++t) {
    const float4* xr = (const float4*)(xh + (((size_t)bl * TT + t) * DD + d0) * 3);
    float4 xb[12];
    #pragma unroll
    for (int i = 0; i < 12; ++i) xb[i] = xr[i];
    const float* x = (const float*)xb;
    float a0 = 0.f, a1 = 0.f, a2 = 0.f, a3 = 0.f;
    #pragma unroll
    for (int k = 0; k < 16; k += 4) {
      a0 = fmaf(fmaf(w0, x[(k+0)*3], fmaf(w1, x[(k+0)*3+1], fmaf(w2, x[(k+0)*3+2], b0))), q[k+0], a0);
      a1 = fmaf(fmaf(w0, x[(k+1)*3], fmaf(w1, x[(k+1)*3+1], fmaf(w2, x[(k+1)*3+2], b0))), q[k+1], a1);
      a2 = fmaf(fmaf(w0, x[(k+2)*3], fmaf(w1, x[(k+2)*3+1], fmaf(w2, x[(k+2)*3+2], b0))), q[k+2], a2);
      a3 = fmaf(fmaf(w0, x[(k+3)*3], fmaf(w1, x[(k+3)*3+1], fmaf(w2, x[(k+3)*3+2], b0))), q[k+3], a3);
    }
    part[t][s][c] = (a0 + a1) + (a2 + a3);
  }
  __syncthreads();

  // Block reduction over s: 1152 outputs across 256 threads.
  for (int idx = threadIdx.x; idx < TT * CC; idx += 256) {
    const int t  = idx >> 5;
    const int cc = idx & 31;
    float v = 0.f;
    #pragma unroll
    for (int j = 0; j < 8; ++j) v += part[t][j][cc];
    mqp[(((size_t)bl * TT + t) * 8 + dc) * CC + cc] = v;
  }
}

// ---------------------------------------------------------------------------
// K2: reduce partials -> softmax(relu) -> memory read -> residual.
// grid (96, 4, 4) = 1536 blocks; 256 threads = 256 d-lanes; 8 channels per
// thread in registers (blockIdx.z picks the 8). Prologue: 32 threads reduce
// mqp (8-way over dc) and build att[t][c] in LDS (4.6 KB). Main loop: zero
// cross-thread reduction; att read as float4 LDS broadcast.
// ---------------------------------------------------------------------------
__global__ __launch_bounds__(256) void k_out(const float* __restrict__ xl,
                                             const float* __restrict__ xh,
                                             const float* __restrict__ mqp,
                                             const float* __restrict__ Wq,
                                             const float* __restrict__ bq,
                                             const float* __restrict__ Wc,
                                             const float* __restrict__ bc,
                                             float* __restrict__ out) {
  __shared__ __align__(16) float att[TT][CC];
  const int bl = blockIdx.x;            // 0..95
  const int b = bl / LL, l = bl % LL;
  const int dc = blockIdx.y;            // 0..3 (256-d chunk)
  const int cg = blockIdx.z;            // 0..3 (8-channel group)
  const int tid = threadIdx.x;

  if (tid < CC) {
    const int c = tid;
    const float* p = mqp + (size_t)bl * TT * 8 * CC + c;
    float r[TT];
    float mx = 0.f;                     // relu >= 0 -> 0 is a valid max seed
    for (int t = 0; t < TT; ++t) {
      float v = 0.f;
      #pragma unroll
      for (int s = 0; s < 8; ++s) v += p[(size_t)(t * 8 + s) * CC];
      v = fmaxf(v, 0.f);
      r[t] = v;
      mx = fmaxf(mx, v);
    }
    float ssum = 0.f;
    #pragma unroll
    for (int t = 0; t < TT; ++t) {
      r[t] = __expf(r[t] - mx);
      ssum += r[t];
    }
    const float inv = 1.f / ssum;
    #pragma unroll
    for (int t = 0; t < TT; ++t) att[t][c] = r[t] * inv;
  }
  __syncthreads();

  const int d = dc * 256 + tid;
  const int c0 = cg * 8;

  float w[8][3], bb[8];
  #pragma unroll
  for (int u = 0; u < 8; ++u) {
    w[u][0] = Wc[(c0 + u) * 3 + 0];
    w[u][1] = Wc[(c0 + u) * 3 + 1];
    w[u][2] = Wc[(c0 + u) * 3 + 2];
    bb[u]   = bc[c0 + u];
  }

  float acc[8];
  #pragma unroll
  for (int u = 0; u < 8; ++u) acc[u] = 0.f;

  #pragma unroll 4
  for (int t = 0; t < TT; ++t) {
    const float* p = xh + (((size_t)bl * TT + t) * DD + d) * 3;
    const float x0 = p[0], x1 = p[1], x2 = p[2];
    const float4 a0 = *(const float4*)&att[t][c0 + 0];  // LDS broadcast
    const float4 a1 = *(const float4*)&att[t][c0 + 4];
    acc[0] = fmaf(a0.x, fmaf(w[0][0], x0, fmaf(w[0][1], x1, fmaf(w[0][2], x2, bb[0]))), acc[0]);
    acc[1] = fmaf(a0.y, fmaf(w[1][0], x0, fmaf(w[1][1], x1, fmaf(w[1][2], x2, bb[1]))), acc[1]);
    acc[2] = fmaf(a0.z, fmaf(w[2][0], x0, fmaf(w[2][1], x1, fmaf(w[2][2], x2, bb[2]))), acc[2]);
    acc[3] = fmaf(a0.w, fmaf(w[3][0], x0, fmaf(w[3][1], x1, fmaf(w[3][2], x2, bb[3]))), acc[3]);
    acc[4] = fmaf(a1.x, fmaf(w[4][0], x0, fmaf(w[4][1], x1, fmaf(w[4][2], x2, bb[4]))), acc[4]);
    acc[5] = fmaf(a1.y, fmaf(w[5][0], x0, fmaf(w[5][1], x1, fmaf(w[5][2], x2, bb[5]))), acc[5]);
    acc[6] = fmaf(a1.z, fmaf(w[6][0], x0, fmaf(w[6][1], x1, fmaf(w[6][2], x2, bb[6]))), acc[6]);
    acc[7] = fmaf(a1.w, fmaf(w[7][0], x0, fmaf(w[7][1], x1, fmaf(w[7][2], x2, bb[7]))), acc[7]);
  }

  // Residual q + store (coalesced 1KB per wave per channel).
  const float y0 = xl[((size_t)bl * DD + d) * 3 + 0];
  const float y1 = xl[((size_t)bl * DD + d) * 3 + 1];
  const float y2 = xl[((size_t)bl * DD + d) * 3 + 2];
  #pragma unroll
  for (int u = 0; u < 8; ++u) {
    const int c = c0 + u;
    const float qv = fmaf(Wq[c * 3 + 0], y0,
                     fmaf(Wq[c * 3 + 1], y1,
                     fmaf(Wq[c * 3 + 2], y2, bq[c])));
    out[(((size_t)b * CC + c) * LL + l) * DD + d] = qv + acc[u];
  }
}

// ---------------------------------------------------------------------------
extern "C" void kernel_launch(void* const* d_in, const int* in_sizes, int n_in,
                              void* d_out, int out_size, void* d_ws, size_t ws_size,
                              hipStream_t stream) {
  const float* xl = (const float*)d_in[0];  // (B,L,D,F)
  const float* xh = (const float*)d_in[1];  // (B,L,T,D,F)
  const float* Wq = (const float*)d_in[2];
  const float* bq = (const float*)d_in[3];
  const float* Wm = (const float*)d_in[4];
  const float* bm = (const float*)d_in[5];
  const float* Wc = (const float*)d_in[6];
  const float* bc = (const float*)d_in[7];
  float* out = (float*)d_out;               // (B,C,L,D)

  float* mqp = (float*)d_ws;                // [bl][t][dc=8][c=32] partials, 3.5 MB

  k_mq <<<dim3(BB * LL, 8),    256, 0, stream>>>(xl, xh, Wm, bm, Wq, bq, mqp);
  k_out<<<dim3(BB * LL, 4, 4), 256, 0, stream>>>(xl, xh, mqp, Wq, bq, Wc, bc, out);
}